// Round 2
// baseline (25375.925 us; speedup 1.0000x reference)
//
#include <hip/hip_runtime.h>
#include <cmath>

#define BB 64
#define TT 512
#define II 256
#define HH 1024
#define OO 512

// Transposed h layout: hT4[k/4][b][4] -> element h[b][k] at hT4[(k>>2)*256 + b*4 + (k&3)]
// Each buffer: (HH/4)*BB*4 = 65536 floats = 256 KB. Total ws use: 4 buffers = 1 MB.

// ---------------------------------------------------------------------------
// Pipelined step: blocks 0..127 compute layer-0 step t, blocks 128..255
// compute layer-1 step t-1 (produced by the PREVIOUS launch -> no race).
// Per block: 8 output columns; 4 waves split K; lane = batch index.
// ---------------------------------------------------------------------------
__global__ __launch_bounds__(256) void step_pipe(
    const float* __restrict__ x,                                   // [64][512][256]
    const float* __restrict__ Wih0, const float* __restrict__ Whh0,
    const float* __restrict__ bih0, const float* __restrict__ bhh0,
    const float* __restrict__ Wih1, const float* __restrict__ Whh1,
    const float* __restrict__ bih1, const float* __restrict__ bhh1,
    float* __restrict__ h1a, float* __restrict__ h1b,
    float* __restrict__ h2a, float* __restrict__ h2b,
    int t)
{
    const int lane = threadIdx.x & 63;   // batch
    const int wave = threadIdx.x >> 6;   // K-slice
    __shared__ float Ps[4][64][8];

    float acc[8] = {0.f, 0.f, 0.f, 0.f, 0.f, 0.f, 0.f, 0.f};

    if (blockIdx.x < 128) {
        // ---- layer 0, step t: h1_t = tanh(x_t @ Wih0^T + bih0 + bhh0 + h1_{t-1} @ Whh0^T)
        if (t >= TT) return;
        const int c0 = blockIdx.x * 8;

        if (t > 0) {
            const float* hr = (t & 1) ? h1a : h1b;   // h1_{t-1} at index (t-1)&1
            #pragma unroll 4
            for (int k4 = wave * 64; k4 < wave * 64 + 64; ++k4) {
                const float4 hv = *(const float4*)(hr + k4 * 256 + lane * 4);
                const int k = k4 * 4;
                #pragma unroll
                for (int c = 0; c < 8; ++c) {
                    const float4 wv = *(const float4*)(Whh0 + (size_t)(c0 + c) * HH + k);
                    acc[c] += hv.x * wv.x + hv.y * wv.y + hv.z * wv.z + hv.w * wv.w;
                }
            }
        }
        {
            const float* xrow = x + (size_t)lane * (TT * II) + (size_t)t * II;
            #pragma unroll 4
            for (int k4 = wave * 16; k4 < wave * 16 + 16; ++k4) {
                const float4 xv = *(const float4*)(xrow + k4 * 4);
                const int k = k4 * 4;
                #pragma unroll
                for (int c = 0; c < 8; ++c) {
                    const float4 wv = *(const float4*)(Wih0 + (size_t)(c0 + c) * II + k);
                    acc[c] += xv.x * wv.x + xv.y * wv.y + xv.z * wv.z + xv.w * wv.w;
                }
            }
        }
        *(float4*)&Ps[wave][lane][0] = make_float4(acc[0], acc[1], acc[2], acc[3]);
        *(float4*)&Ps[wave][lane][4] = make_float4(acc[4], acc[5], acc[6], acc[7]);
        __syncthreads();
        if (wave == 0) {
            float* hw = (t & 1) ? h1b : h1a;         // write index t&1
            float o[8];
            #pragma unroll
            for (int c = 0; c < 8; ++c) {
                float s = Ps[0][lane][c] + Ps[1][lane][c]
                        + Ps[2][lane][c] + Ps[3][lane][c];
                s += bih0[c0 + c] + bhh0[c0 + c];
                o[c] = tanhf(s);
            }
            *(float4*)(hw + (size_t)(c0 / 4 + 0) * 256 + lane * 4) = make_float4(o[0], o[1], o[2], o[3]);
            *(float4*)(hw + (size_t)(c0 / 4 + 1) * 256 + lane * 4) = make_float4(o[4], o[5], o[6], o[7]);
        }
    } else {
        // ---- layer 1, step s = t-1: h2_s = tanh(h1_s @ Wih1^T + bih1 + bhh1 + h2_{s-1} @ Whh1^T)
        const int s = t - 1;
        if (s < 0) return;
        const int c0 = (blockIdx.x - 128) * 8;

        {
            const float* h1r = (s & 1) ? h1b : h1a;  // h1_s at index s&1 (written last launch)
            #pragma unroll 4
            for (int k4 = wave * 64; k4 < wave * 64 + 64; ++k4) {
                const float4 hv = *(const float4*)(h1r + k4 * 256 + lane * 4);
                const int k = k4 * 4;
                #pragma unroll
                for (int c = 0; c < 8; ++c) {
                    const float4 wv = *(const float4*)(Wih1 + (size_t)(c0 + c) * HH + k);
                    acc[c] += hv.x * wv.x + hv.y * wv.y + hv.z * wv.z + hv.w * wv.w;
                }
            }
        }
        if (s > 0) {
            const float* h2r = (s & 1) ? h2a : h2b;  // h2_{s-1} at index (s-1)&1
            #pragma unroll 4
            for (int k4 = wave * 64; k4 < wave * 64 + 64; ++k4) {
                const float4 hv = *(const float4*)(h2r + k4 * 256 + lane * 4);
                const int k = k4 * 4;
                #pragma unroll
                for (int c = 0; c < 8; ++c) {
                    const float4 wv = *(const float4*)(Whh1 + (size_t)(c0 + c) * HH + k);
                    acc[c] += hv.x * wv.x + hv.y * wv.y + hv.z * wv.z + hv.w * wv.w;
                }
            }
        }
        *(float4*)&Ps[wave][lane][0] = make_float4(acc[0], acc[1], acc[2], acc[3]);
        *(float4*)&Ps[wave][lane][4] = make_float4(acc[4], acc[5], acc[6], acc[7]);
        __syncthreads();
        if (wave == 0) {
            float* h2w = (s & 1) ? h2b : h2a;        // write index s&1
            float o[8];
            #pragma unroll
            for (int c = 0; c < 8; ++c) {
                float v = Ps[0][lane][c] + Ps[1][lane][c]
                        + Ps[2][lane][c] + Ps[3][lane][c];
                v += bih1[c0 + c] + bhh1[c0 + c];
                o[c] = tanhf(v);
            }
            *(float4*)(h2w + (size_t)(c0 / 4 + 0) * 256 + lane * 4) = make_float4(o[0], o[1], o[2], o[3]);
            *(float4*)(h2w + (size_t)(c0 / 4 + 1) * 256 + lane * 4) = make_float4(o[4], o[5], o[6], o[7]);
        }
    }
}

// ---------------------------------------------------------------------------
// out[b][o] = sum_k h2[b][k] * Wfc[o][k] + bfc[o], h2 in hT4 layout.
// Grid: 64 WGs (8 cols each) x 256 threads.
// ---------------------------------------------------------------------------
__global__ __launch_bounds__(256) void fc_kernel(
    const float* __restrict__ h2, const float* __restrict__ Wfc,
    const float* __restrict__ bfc, float* __restrict__ out)
{
    const int lane = threadIdx.x & 63;
    const int wave = threadIdx.x >> 6;
    const int c0 = blockIdx.x * 8;
    __shared__ float Ps[4][64][8];

    float acc[8] = {0.f, 0.f, 0.f, 0.f, 0.f, 0.f, 0.f, 0.f};
    #pragma unroll 4
    for (int k4 = wave * 64; k4 < wave * 64 + 64; ++k4) {
        const float4 hv = *(const float4*)(h2 + k4 * 256 + lane * 4);
        const int k = k4 * 4;
        #pragma unroll
        for (int c = 0; c < 8; ++c) {
            const float4 wv = *(const float4*)(Wfc + (size_t)(c0 + c) * HH + k);
            acc[c] += hv.x * wv.x + hv.y * wv.y + hv.z * wv.z + hv.w * wv.w;
        }
    }
    *(float4*)&Ps[wave][lane][0] = make_float4(acc[0], acc[1], acc[2], acc[3]);
    *(float4*)&Ps[wave][lane][4] = make_float4(acc[4], acc[5], acc[6], acc[7]);
    __syncthreads();
    if (wave == 0) {
        float o[8];
        #pragma unroll
        for (int c = 0; c < 8; ++c) {
            float s = Ps[0][lane][c] + Ps[1][lane][c] + Ps[2][lane][c] + Ps[3][lane][c];
            o[c] = s + bfc[c0 + c];
        }
        *(float4*)(out + (size_t)lane * OO + c0)     = make_float4(o[0], o[1], o[2], o[3]);
        *(float4*)(out + (size_t)lane * OO + c0 + 4) = make_float4(o[4], o[5], o[6], o[7]);
    }
}

// ---------------------------------------------------------------------------
extern "C" void kernel_launch(void* const* d_in, const int* in_sizes, int n_in,
                              void* d_out, int out_size, void* d_ws, size_t ws_size,
                              hipStream_t stream) {
    const float* x    = (const float*)d_in[0];
    const float* Wih0 = (const float*)d_in[1];
    const float* Whh0 = (const float*)d_in[2];
    const float* bih0 = (const float*)d_in[3];
    const float* bhh0 = (const float*)d_in[4];
    const float* Wih1 = (const float*)d_in[5];
    const float* Whh1 = (const float*)d_in[6];
    const float* bih1 = (const float*)d_in[7];
    const float* bhh1 = (const float*)d_in[8];
    const float* Wfc  = (const float*)d_in[9];
    const float* bfc  = (const float*)d_in[10];
    float* out = (float*)d_out;

    const size_t HB = (size_t)HH * BB;      // 65536 floats per h buffer
    float* h1a = (float*)d_ws;
    float* h1b = h1a + HB;
    float* h2a = h1b + HB;
    float* h2b = h2a + HB;                  // total 1 MB of d_ws

    // Pipelined recurrence: launch t runs L0(t) and L1(t-1).
    for (int t = 0; t <= TT; ++t) {
        hipLaunchKernelGGL(step_pipe, dim3(256), dim3(256), 0, stream,
                           x, Wih0, Whh0, bih0, bhh0, Wih1, Whh1, bih1, bhh1,
                           h1a, h1b, h2a, h2b, t);
    }

    // h2_{511} sits at index 511&1 = 1 -> h2b.
    hipLaunchKernelGGL(fc_kernel, dim3(OO / 8), dim3(256), 0, stream,
                       h2b, Wfc, bfc, out);
}

// Round 3
// 17675.735 us; speedup vs baseline: 1.4356x; 1.4356x over previous
//
#include <hip/hip_runtime.h>
#include <cmath>

#define BB 64
#define TT 512
#define II 256
#define HH 1024
#define OO 512

// Transposed h layout: hT4[k/4][b][4] -> element h[b][k] at hT4[(k>>2)*256 + b*4 + (k&3)]
// Each buffer: 65536 floats = 256 KB. Total ws use: 4 buffers = 1 MB.

// ---------------------------------------------------------------------------
// Pipelined step, 512 WGs x 256 threads (2 WG/CU):
//   blocks   0..255 : layer 0, step t   (4 output cols each)
//   blocks 256..511 : layer 1, step t-1 (4 output cols each)
// Per WG: stage its 4 weight rows into LDS (coalesced float4 -> ds_write),
// then lane=batch, wave=K-slice inner loop with broadcast LDS weight reads.
// ---------------------------------------------------------------------------
__global__ __launch_bounds__(256) void step_pipe(
    const float* __restrict__ x,                                   // [64][512][256]
    const float* __restrict__ Wih0, const float* __restrict__ Whh0,
    const float* __restrict__ bih0, const float* __restrict__ bhh0,
    const float* __restrict__ Wih1, const float* __restrict__ Whh1,
    const float* __restrict__ bih1, const float* __restrict__ bhh1,
    float* __restrict__ h1a, float* __restrict__ h1b,
    float* __restrict__ h2a, float* __restrict__ h2b,
    int t)
{
    const int lane = threadIdx.x & 63;   // batch index
    const int wave = threadIdx.x >> 6;   // K-slice / staging row
    __shared__ float Ws[4][2048];        // 32 KB: 4 weight rows (concat per layer)
    __shared__ float Ps[4][64][4];       // partial sums

    float acc[4] = {0.f, 0.f, 0.f, 0.f};

    if (blockIdx.x < 256) {
        // ---- layer 0, step t: h1_t = tanh(x_t@Wih0^T + b + h1_{t-1}@Whh0^T)
        if (t >= TT) return;
        const int c0 = blockIdx.x * 4;

        // stage: wave stages row (c0+wave): Wih0 row [0,256) + Whh0 row [256,1280)
        {
            const float* ri = Wih0 + (size_t)(c0 + wave) * II;
            *(float4*)&Ws[wave][lane * 4] = *(const float4*)(ri + lane * 4);
            const float* rh = Whh0 + (size_t)(c0 + wave) * HH;
            #pragma unroll
            for (int r = 0; r < 4; ++r)
                *(float4*)&Ws[wave][256 + r * 256 + lane * 4] =
                    *(const float4*)(rh + r * 256 + lane * 4);
        }
        __syncthreads();

        // x part: wave covers k in [wave*64, wave*64+64)
        {
            const float* xrow = x + (size_t)lane * (TT * II) + (size_t)t * II;
            #pragma unroll
            for (int k4 = wave * 16; k4 < wave * 16 + 16; ++k4) {
                const float4 xv = *(const float4*)(xrow + k4 * 4);
                #pragma unroll
                for (int c = 0; c < 4; ++c) {
                    const float4 wv = *(const float4*)&Ws[c][k4 * 4];
                    acc[c] += xv.x * wv.x + xv.y * wv.y + xv.z * wv.z + xv.w * wv.w;
                }
            }
        }
        // h part: wave covers k in [wave*256, wave*256+256)
        if (t > 0) {
            const float* hr = (t & 1) ? h1a : h1b;   // h1_{t-1} at slot (t-1)&1
            #pragma unroll 8
            for (int k4 = wave * 64; k4 < wave * 64 + 64; ++k4) {
                const float4 hv = *(const float4*)(hr + k4 * 256 + lane * 4);
                #pragma unroll
                for (int c = 0; c < 4; ++c) {
                    const float4 wv = *(const float4*)&Ws[c][256 + k4 * 4];
                    acc[c] += hv.x * wv.x + hv.y * wv.y + hv.z * wv.z + hv.w * wv.w;
                }
            }
        }

        *(float4*)&Ps[wave][lane][0] = make_float4(acc[0], acc[1], acc[2], acc[3]);
        __syncthreads();
        if (wave == 0) {
            float* hw = (t & 1) ? h1b : h1a;         // write slot t&1
            float o[4];
            #pragma unroll
            for (int c = 0; c < 4; ++c) {
                float s = Ps[0][lane][c] + Ps[1][lane][c]
                        + Ps[2][lane][c] + Ps[3][lane][c];
                s += bih0[c0 + c] + bhh0[c0 + c];
                o[c] = tanhf(s);
            }
            *(float4*)(hw + (size_t)(c0 / 4) * 256 + lane * 4) =
                make_float4(o[0], o[1], o[2], o[3]);
        }
    } else {
        // ---- layer 1, step s=t-1: h2_s = tanh(h1_s@Wih1^T + b + h2_{s-1}@Whh1^T)
        const int s = t - 1;
        if (s < 0) return;
        const int c0 = (blockIdx.x - 256) * 4;

        // stage: wave stages row (c0+wave): Wih1 row [0,1024) + Whh1 row [1024,2048)
        {
            const float* ra = Wih1 + (size_t)(c0 + wave) * HH;
            const float* rb = Whh1 + (size_t)(c0 + wave) * HH;
            #pragma unroll
            for (int r = 0; r < 4; ++r)
                *(float4*)&Ws[wave][r * 256 + lane * 4] =
                    *(const float4*)(ra + r * 256 + lane * 4);
            #pragma unroll
            for (int r = 0; r < 4; ++r)
                *(float4*)&Ws[wave][1024 + r * 256 + lane * 4] =
                    *(const float4*)(rb + r * 256 + lane * 4);
        }
        __syncthreads();

        {
            const float* h1r = (s & 1) ? h1b : h1a;  // h1_s at slot s&1
            #pragma unroll 8
            for (int k4 = wave * 64; k4 < wave * 64 + 64; ++k4) {
                const float4 hv = *(const float4*)(h1r + k4 * 256 + lane * 4);
                #pragma unroll
                for (int c = 0; c < 4; ++c) {
                    const float4 wv = *(const float4*)&Ws[c][k4 * 4];
                    acc[c] += hv.x * wv.x + hv.y * wv.y + hv.z * wv.z + hv.w * wv.w;
                }
            }
        }
        if (s > 0) {
            const float* h2r = (s & 1) ? h2a : h2b;  // h2_{s-1} at slot (s-1)&1
            #pragma unroll 8
            for (int k4 = wave * 64; k4 < wave * 64 + 64; ++k4) {
                const float4 hv = *(const float4*)(h2r + k4 * 256 + lane * 4);
                #pragma unroll
                for (int c = 0; c < 4; ++c) {
                    const float4 wv = *(const float4*)&Ws[c][1024 + k4 * 4];
                    acc[c] += hv.x * wv.x + hv.y * wv.y + hv.z * wv.z + hv.w * wv.w;
                }
            }
        }

        *(float4*)&Ps[wave][lane][0] = make_float4(acc[0], acc[1], acc[2], acc[3]);
        __syncthreads();
        if (wave == 0) {
            float* h2w = (s & 1) ? h2b : h2a;        // write slot s&1
            float o[4];
            #pragma unroll
            for (int c = 0; c < 4; ++c) {
                float v = Ps[0][lane][c] + Ps[1][lane][c]
                        + Ps[2][lane][c] + Ps[3][lane][c];
                v += bih1[c0 + c] + bhh1[c0 + c];
                o[c] = tanhf(v);
            }
            *(float4*)(h2w + (size_t)(c0 / 4) * 256 + lane * 4) =
                make_float4(o[0], o[1], o[2], o[3]);
        }
    }
}

// ---------------------------------------------------------------------------
// out[b][o] = sum_k h2[b][k] * Wfc[o][k] + bfc[o], h2 in hT4 layout.
// ---------------------------------------------------------------------------
__global__ __launch_bounds__(256) void fc_kernel(
    const float* __restrict__ h2, const float* __restrict__ Wfc,
    const float* __restrict__ bfc, float* __restrict__ out)
{
    const int lane = threadIdx.x & 63;
    const int wave = threadIdx.x >> 6;
    const int c0 = blockIdx.x * 8;
    __shared__ float Ps[4][64][8];

    float acc[8] = {0.f, 0.f, 0.f, 0.f, 0.f, 0.f, 0.f, 0.f};
    #pragma unroll 4
    for (int k4 = wave * 64; k4 < wave * 64 + 64; ++k4) {
        const float4 hv = *(const float4*)(h2 + k4 * 256 + lane * 4);
        const int k = k4 * 4;
        #pragma unroll
        for (int c = 0; c < 8; ++c) {
            const float4 wv = *(const float4*)(Wfc + (size_t)(c0 + c) * HH + k);
            acc[c] += hv.x * wv.x + hv.y * wv.y + hv.z * wv.z + hv.w * wv.w;
        }
    }
    *(float4*)&Ps[wave][lane][0] = make_float4(acc[0], acc[1], acc[2], acc[3]);
    *(float4*)&Ps[wave][lane][4] = make_float4(acc[4], acc[5], acc[6], acc[7]);
    __syncthreads();
    if (wave == 0) {
        float o[8];
        #pragma unroll
        for (int c = 0; c < 8; ++c) {
            float s = Ps[0][lane][c] + Ps[1][lane][c] + Ps[2][lane][c] + Ps[3][lane][c];
            o[c] = s + bfc[c0 + c];
        }
        *(float4*)(out + (size_t)lane * OO + c0)     = make_float4(o[0], o[1], o[2], o[3]);
        *(float4*)(out + (size_t)lane * OO + c0 + 4) = make_float4(o[4], o[5], o[6], o[7]);
    }
}

// ---------------------------------------------------------------------------
extern "C" void kernel_launch(void* const* d_in, const int* in_sizes, int n_in,
                              void* d_out, int out_size, void* d_ws, size_t ws_size,
                              hipStream_t stream) {
    const float* x    = (const float*)d_in[0];
    const float* Wih0 = (const float*)d_in[1];
    const float* Whh0 = (const float*)d_in[2];
    const float* bih0 = (const float*)d_in[3];
    const float* bhh0 = (const float*)d_in[4];
    const float* Wih1 = (const float*)d_in[5];
    const float* Whh1 = (const float*)d_in[6];
    const float* bih1 = (const float*)d_in[7];
    const float* bhh1 = (const float*)d_in[8];
    const float* Wfc  = (const float*)d_in[9];
    const float* bfc  = (const float*)d_in[10];
    float* out = (float*)d_out;

    const size_t HB = (size_t)HH * BB;      // 65536 floats per h buffer
    float* h1a = (float*)d_ws;
    float* h1b = h1a + HB;
    float* h2a = h1b + HB;
    float* h2b = h2a + HB;                  // total 1 MB of d_ws

    // Pipelined recurrence: launch t runs L0(t) and L1(t-1).
    for (int t = 0; t <= TT; ++t) {
        hipLaunchKernelGGL(step_pipe, dim3(512), dim3(256), 0, stream,
                           x, Wih0, Whh0, bih0, bhh0, Wih1, Whh1, bih1, bhh1,
                           h1a, h1b, h2a, h2b, t);
    }

    // h2_{511} sits at slot 511&1 = 1 -> h2b.
    hipLaunchKernelGGL(fc_kernel, dim3(OO / 8), dim3(256), 0, stream,
                       h2b, Wfc, bfc, out);
}